// Round 2
// 100.583 us; speedup vs baseline: 1.0117x; 1.0117x over previous
//
#include <hip/hip_runtime.h>
#include <hip/hip_bf16.h>

#define B_ 32
#define T_ 2048
#define D_ 1024
#define A_ 128

typedef __attribute__((ext_vector_type(8))) short bf16x8;
typedef __attribute__((ext_vector_type(4))) float f32x4;
typedef __attribute__((ext_vector_type(4))) unsigned u32x4;

static __device__ __forceinline__ unsigned short f2bf(float f) {
  union { float f; unsigned u; } v; v.f = f;
  unsigned r = v.u + 0x7FFFu + ((v.u >> 16) & 1u);
  return (unsigned short)(r >> 16);
}

// packed f32x2 -> bf16x2 (RNE); compiler emits v_cvt_pk_bf16_f32
static __device__ __forceinline__ unsigned cvt2u(float lo, float hi) {
  __hip_bfloat162 h2 = __float22bfloat162_rn(make_float2(lo, hi));
  unsigned u;
  __builtin_memcpy(&u, &h2, 4);
  return u;
}

// barrier that does NOT drain vmcnt (keeps global_load_lds prefetch in flight)
static __device__ __forceinline__ void barrier_lds() {
  asm volatile("s_waitcnt lgkmcnt(0)\n\ts_barrier" ::: "memory");
}

#define GLOAD_LDS16(g, l)                                                        \
  __builtin_amdgcn_global_load_lds(                                              \
      (const __attribute__((address_space(1))) void*)(g),                        \
      (__attribute__((address_space(3))) void*)(l), 16, 0, 0)

// ---------------- prep: Wt[a][d] = bf16(Ws[d][a]) ----------------
__global__ __launch_bounds__(256) void k_prep(const float* __restrict__ Ws,
                                              unsigned short* __restrict__ Wt) {
  int i = blockIdx.x * 256 + threadIdx.x;  // coalesced write
  int a = i >> 10, d = i & 1023;
  Wt[i] = f2bf(Ws[(size_t)d * A_ + a]);
}

// ---------------- fused: scores -> exp -> weighted x accumulation ----------------
// grid (8, 32): blockIdx.x = t-slice (256 t each), blockIdx.y = b. 512 thr (8 waves).
// One block/CU (128.5 KB LDS). Per chunk of 16 t: MFMA scores, e=exp(s), acc += e*x.
#define LDR 1028  // floats per LDS row: 4 KB data + 16 B pad (A-frag reads 2-way max)

__global__ __launch_bounds__(512, 2) void k_fused(const float* __restrict__ x,
                                                  const unsigned short* __restrict__ Wt,
                                                  const float* __restrict__ bs,
                                                  const float* __restrict__ us,
                                                  float* __restrict__ part,
                                                  float* __restrict__ Zp) {
  __shared__ __align__(16) float xb2[2][16 * LDR];  // 131584 B double buffer
  __shared__ float sc_part[16 * 8];
  __shared__ float e_lds[16];

  const int tid  = threadIdx.x;
  const int w    = tid >> 6;
  const int lane = tid & 63;
  const int lrow = lane & 15;
  const int g    = lane >> 4;
  const int sub  = blockIdx.x;
  const int b    = blockIdx.y;

  // W^T fragments for this wave's 16 a-columns, resident in registers (128 VGPR)
  const int a_col = w * 16 + lrow;
  bf16x8 wreg[32];
  {
    const unsigned short* wr = Wt + (size_t)a_col * D_ + g * 8;
#pragma unroll
    for (int kt = 0; kt < 32; ++kt) wreg[kt] = *(const bf16x8*)(wr + kt * 32);
  }
  const float bsv = bs[a_col];
  const float usv = us[a_col];

  const float* gxb = x + ((size_t)b * T_ + (size_t)sub * 256) * D_;

  // stage chunk 0 (each wave: rows 2w..2w+1, 4x 1KB async DMA per row)
#pragma unroll
  for (int rr = 0; rr < 2; ++rr) {
    const int row = w * 2 + rr;
    const float* gp = gxb + (size_t)row * D_ + lane * 4;
    float* lp = &xb2[0][row * LDR];
#pragma unroll
    for (int q = 0; q < 4; ++q) GLOAD_LDS16(gp + q * 256, lp + q * 256);
  }
  __syncthreads();

  float a0 = 0.f, a1 = 0.f, zacc = 0.f;

  for (int i = 0; i < 16; ++i) {
    float* xb = xb2[i & 1];

    // prefetch next chunk into the other buffer (async; drains at end barrier)
    if (i < 15) {
      const float* gc = gxb + (size_t)(i + 1) * 16 * D_;
      float* nb = xb2[(i + 1) & 1];
#pragma unroll
      for (int rr = 0; rr < 2; ++rr) {
        const int row = w * 2 + rr;
        const float* gp = gc + (size_t)row * D_ + lane * 4;
        float* lp = nb + row * LDR;
#pragma unroll
        for (int q = 0; q < 4; ++q) GLOAD_LDS16(gp + q * 256, lp + q * 256);
      }
    }

    // GEMM: z[16 t][16 a-cols of this wave] over K=1024 (A from LDS f32->bf16)
    f32x4 accm = (f32x4)0.f;
    const float* arow = xb + lrow * LDR + g * 8;
#pragma unroll
    for (int kt = 0; kt < 32; ++kt) {
      float4 lo = *(const float4*)(arow + kt * 32);
      float4 hi = *(const float4*)(arow + kt * 32 + 4);
      union { u32x4 u; bf16x8 v; } af;
      af.u[0] = cvt2u(lo.x, lo.y);
      af.u[1] = cvt2u(lo.z, lo.w);
      af.u[2] = cvt2u(hi.x, hi.y);
      af.u[3] = cvt2u(hi.z, hi.w);
      accm = __builtin_amdgcn_mfma_f32_16x16x32_bf16(af.v, wreg[kt], accm, 0, 0, 0);
    }

    // per-wave score partial: sum over 16 cols of us*tanh(z+bs)
    // C layout: col = lane&15 (a), row = g*4 + r (t)
#pragma unroll
    for (int r = 0; r < 4; ++r) {
      float p = usv * tanhf(accm[r] + bsv);
#pragma unroll
      for (int o = 1; o < 16; o <<= 1) p += __shfl_xor(p, o, 64);
      if (lrow == 0) sc_part[(g * 4 + r) * 8 + w] = p;
    }
    barrier_lds();

    // |score| <= ||us||_1 ~ 9 => exp without max-shift is safe in f32
    if (tid < 16) {
      float s = 0.f;
#pragma unroll
      for (int ww = 0; ww < 8; ++ww) s += sc_part[tid * 8 + ww];
      e_lds[tid] = expf(s);
    }
    barrier_lds();

    // accumulate: each thread owns d = 2*tid, 2*tid+1 (f32 x straight from LDS)
    const float* xd = xb + tid * 2;
#pragma unroll
    for (int t = 0; t < 16; ++t) {
      const float ev = e_lds[t];
      a0 = fmaf(ev, xd[t * LDR], a0);
      a1 = fmaf(ev, xd[t * LDR + 1], a1);
      zacc += ev;  // uniform across threads; thread 0 writes
    }
    __syncthreads();  // drains prefetch vmcnt + protects buffer reuse
  }

  float* pp = part + ((size_t)sub * B_ + b) * D_ + tid * 2;
  *(float2*)pp = make_float2(a0, a1);
  if (tid == 0) Zp[b * 8 + sub] = zacc;
}

// ---------------- reduce 8 slice-partials, divide by Z ----------------
__global__ __launch_bounds__(256) void k_reduce(const float* __restrict__ part,
                                                const float* __restrict__ Zp,
                                                float* __restrict__ out) {
  const int i = blockIdx.x * 256 + threadIdx.x;  // 0..32767
  const int b = i >> 10, d = i & 1023;
  float zs = 0.f;
#pragma unroll
  for (int s = 0; s < 8; ++s) zs += Zp[b * 8 + s];
  float acc = 0.f;
#pragma unroll
  for (int s = 0; s < 8; ++s) acc += part[((size_t)s * B_ + b) * D_ + d];
  out[i] = acc / zs;
}

extern "C" void kernel_launch(void* const* d_in, const int* in_sizes, int n_in,
                              void* d_out, int out_size, void* d_ws, size_t ws_size,
                              hipStream_t stream) {
  const float* x  = (const float*)d_in[0];
  const float* Ws = (const float*)d_in[1];
  const float* bs = (const float*)d_in[2];
  const float* us = (const float*)d_in[3];
  float* out = (float*)d_out;

  char* ws = (char*)d_ws;
  unsigned short* Wt = (unsigned short*)ws;                       // 256 KB
  float* part = (float*)(ws + (256 << 10));                       // 1 MB
  float* Zp   = (float*)(ws + (256 << 10) + (1 << 20));           // 1 KB

  k_prep<<<512, 256, 0, stream>>>(Ws, Wt);
  k_fused<<<dim3(8, B_), 512, 0, stream>>>(x, Wt, bs, us, part, Zp);
  k_reduce<<<(B_ * D_) / 256, 256, 0, stream>>>(part, Zp, out);
}

// Round 3
// 73.348 us; speedup vs baseline: 1.3873x; 1.3713x over previous
//
#include <hip/hip_runtime.h>
#include <hip/hip_bf16.h>

#define B_ 32
#define T_ 2048
#define D_ 1024
#define A_ 128

typedef __attribute__((ext_vector_type(8))) short bf16x8;
typedef __attribute__((ext_vector_type(4))) float f32x4;

static __device__ __forceinline__ unsigned short f2bf(float f) {
  union { float f; unsigned u; } v; v.f = f;
  unsigned r = v.u + 0x7FFFu + ((v.u >> 16) & 1u);
  return (unsigned short)(r >> 16);
}

// packed f32x2 -> bf16x2 (RNE); compiler emits v_cvt_pk_bf16_f32
static __device__ __forceinline__ unsigned cvt2u(float lo, float hi) {
  __hip_bfloat162 h2 = __float22bfloat162_rn(make_float2(lo, hi));
  unsigned u;
  __builtin_memcpy(&u, &h2, 4);
  return u;
}

// barrier that only drains LDS ops (keeps prefetch global loads in flight)
static __device__ __forceinline__ void barrier_lds() {
  asm volatile("s_waitcnt lgkmcnt(0)\n\ts_barrier" ::: "memory");
}

// ---------------- prep: Wt[a][d] = bf16(Ws[d][a]) ----------------
__global__ __launch_bounds__(256) void k_prep(const float* __restrict__ Ws,
                                              unsigned short* __restrict__ Wt) {
  int i = blockIdx.x * 256 + threadIdx.x;  // coalesced write
  int a = i >> 10, d = i & 1023;
  Wt[i] = f2bf(Ws[(size_t)d * A_ + a]);
}

// ---------------- fused: scores -> exp -> weighted x accumulation ----------------
// grid (8, 32): blockIdx.x = t-slice (256 t), blockIdx.y = b. 512 thr (8 waves), 1 blk/CU.
// Per 16-t chunk: reg-prefetch next chunk; GEMM scores from bf16 A-buffer (converted
// ONCE, not per-wave); exp; exact f32 accumulate from f32 LDS copy.
#define LDRF 1028  // f32 row stride (4112 B): +16B pad, conflict-free b128/b64
#define LDRB 1032  // bf16 row stride in shorts (2064 B): +16B pad

__global__ __launch_bounds__(512, 2) void k_fused(const float* __restrict__ x,
                                                  const unsigned short* __restrict__ Wt,
                                                  const float* __restrict__ bs,
                                                  const float* __restrict__ us,
                                                  float* __restrict__ part,
                                                  float* __restrict__ Zp) {
  __shared__ __align__(16) float xb[16 * LDRF];            // 65,792 B (exact f32 chunk)
  __shared__ __align__(16) unsigned short ab[16 * LDRB];   // 33,024 B (bf16 A-buffer)
  __shared__ float sc_part[16 * 8];
  __shared__ float e_lds[16];

  const int tid  = threadIdx.x;
  const int w    = tid >> 6;
  const int lane = tid & 63;
  const int lrow = lane & 15;
  const int g    = lane >> 4;
  const int sub  = blockIdx.x;
  const int b    = blockIdx.y;

  // W^T fragments for this wave's 16 a-columns, resident in registers (128 VGPR)
  const int a_col = w * 16 + lrow;
  bf16x8 wreg[32];
  {
    const unsigned short* wr = Wt + (size_t)a_col * D_ + g * 8;
#pragma unroll
    for (int kt = 0; kt < 32; ++kt) wreg[kt] = *(const bf16x8*)(wr + kt * 32);
  }
  const float bsv = bs[a_col];
  const float usv = us[a_col];

  // staging assignment: row srow (0..15), cols scol+q*128, q=0..7 (coalesced 512B/seg)
  const int srow = w * 2 + (lane >> 5);
  const int scol = (lane & 31) * 4;
  const float* gx = x + ((size_t)b * T_ + (size_t)sub * 256) * D_;

  float4 st[8];
  // prologue: chunk 0 -> regs -> LDS (f32 + bf16)
#pragma unroll
  for (int q = 0; q < 8; ++q)
    st[q] = *(const float4*)(gx + (size_t)srow * D_ + scol + q * 128);
#pragma unroll
  for (int q = 0; q < 8; ++q) {
    *(float4*)(&xb[srow * LDRF + scol + q * 128]) = st[q];
    unsigned lo = cvt2u(st[q].x, st[q].y);
    unsigned hi = cvt2u(st[q].z, st[q].w);
    *(uint2*)(&ab[srow * LDRB + scol + q * 128]) = make_uint2(lo, hi);
  }
  __syncthreads();

  float a0 = 0.f, a1 = 0.f, zacc = 0.f;

  for (int i = 0; i < 16; ++i) {
    // issue next-chunk global loads NOW; they land during this chunk's compute
    if (i < 15) {
      const float* gc = gx + (size_t)(i + 1) * 16 * D_;
#pragma unroll
      for (int q = 0; q < 8; ++q)
        st[q] = *(const float4*)(gc + (size_t)srow * D_ + scol + q * 128);
    }
    __builtin_amdgcn_sched_barrier(0);  // pin load issue above the compute

    // GEMM: z[16 t][16 a-cols of this wave] over K=1024, A-frags bf16 from ab
    f32x4 accm = (f32x4)0.f;
    const unsigned short* arow = ab + lrow * LDRB + g * 8;
#pragma unroll
    for (int kt = 0; kt < 32; ++kt) {
      bf16x8 af = *(const bf16x8*)(arow + kt * 32);
      accm = __builtin_amdgcn_mfma_f32_16x16x32_bf16(af, wreg[kt], accm, 0, 0, 0);
    }

    // per-wave score partial: sum over this wave's 16 a of us*tanh(z+bs)
    // C layout: col = lane&15 (a), row = g*4 + r (t)
#pragma unroll
    for (int r = 0; r < 4; ++r) {
      float p = usv * tanhf(accm[r] + bsv);
#pragma unroll
      for (int o = 1; o < 16; o <<= 1) p += __shfl_xor(p, o, 64);
      if (lrow == 0) sc_part[(g * 4 + r) * 8 + w] = p;
    }
    barrier_lds();

    // |score| <= ||us||_1 ~ 9 => exp without max-shift is safe in f32
    if (tid < 16) {
      float s = 0.f;
#pragma unroll
      for (int ww = 0; ww < 8; ++ww) s += sc_part[tid * 8 + ww];
      e_lds[tid] = expf(s);
    }
    barrier_lds();

    // exact f32 accumulate: thread owns d = 2*tid, 2*tid+1
    const float* xd = xb + tid * 2;
#pragma unroll
    for (int t = 0; t < 16; ++t) {
      const float2 v = *(const float2*)(xd + t * LDRF);
      const float ev = e_lds[t];
      a0 = fmaf(ev, v.x, a0);
      a1 = fmaf(ev, v.y, a1);
      zacc += ev;  // uniform across threads; thread 0 writes
    }
    __syncthreads();  // chunk i fully consumed (also waits staged loads)

    if (i < 15) {
      // write staged regs: f32 copy + bf16 copy (converted once per element)
#pragma unroll
      for (int q = 0; q < 8; ++q) {
        *(float4*)(&xb[srow * LDRF + scol + q * 128]) = st[q];
        unsigned lo = cvt2u(st[q].x, st[q].y);
        unsigned hi = cvt2u(st[q].z, st[q].w);
        *(uint2*)(&ab[srow * LDRB + scol + q * 128]) = make_uint2(lo, hi);
      }
      __syncthreads();
    }
  }

  float* pp = part + ((size_t)sub * B_ + b) * D_ + tid * 2;
  *(float2*)pp = make_float2(a0, a1);
  if (tid == 0) Zp[b * 8 + sub] = zacc;
}

// ---------------- reduce 8 slice-partials, divide by Z ----------------
__global__ __launch_bounds__(256) void k_reduce(const float* __restrict__ part,
                                                const float* __restrict__ Zp,
                                                float* __restrict__ out) {
  const int i = blockIdx.x * 256 + threadIdx.x;  // 0..32767
  const int b = i >> 10, d = i & 1023;
  float zs = 0.f;
#pragma unroll
  for (int s = 0; s < 8; ++s) zs += Zp[b * 8 + s];
  float acc = 0.f;
#pragma unroll
  for (int s = 0; s < 8; ++s) acc += part[((size_t)s * B_ + b) * D_ + d];
  out[i] = acc / zs;
}

extern "C" void kernel_launch(void* const* d_in, const int* in_sizes, int n_in,
                              void* d_out, int out_size, void* d_ws, size_t ws_size,
                              hipStream_t stream) {
  const float* x  = (const float*)d_in[0];
  const float* Ws = (const float*)d_in[1];
  const float* bs = (const float*)d_in[2];
  const float* us = (const float*)d_in[3];
  float* out = (float*)d_out;

  char* ws = (char*)d_ws;
  unsigned short* Wt = (unsigned short*)ws;                 // 256 KB
  float* part = (float*)(ws + (256 << 10));                 // 1 MB
  float* Zp   = (float*)(ws + (256 << 10) + (1 << 20));     // 1 KB

  k_prep<<<512, 256, 0, stream>>>(Ws, Wt);
  k_fused<<<dim3(8, B_), 512, 0, stream>>>(x, Wt, bs, us, part, Zp);
  k_reduce<<<(B_ * D_) / 256, 256, 0, stream>>>(part, Zp, out);
}